// Round 8
// baseline (56.714 us; speedup 1.0000x reference)
//
#include <hip/hip_runtime.h>
#include <hip/hip_bf16.h>

typedef unsigned int   u32;
typedef unsigned short u16;

#define NN   8192
#define DD   128
#define CCH  32            // column chunks
#define CHUNK (NN / CCH)   // 256 columns per block (== blockDim)
#define NTJ  (CHUNK / 32)  // 8 j-tiles of 32 rows
#define NIB  (NN / 256)    // 32 i-blocks

#define LOG2E 1.4426950408889634f
#define LN2F  0.6931471805599453f
#define BIAS  32.0f

typedef __bf16 bf16x8 __attribute__((ext_vector_type(8)));
typedef float  f32x16 __attribute__((ext_vector_type(16)));
typedef float  f32x2  __attribute__((ext_vector_type(2)));

__device__ __forceinline__ u16 f2bf(float x) {
    u32 u = __float_as_uint(x);
    u += 0x7fffu + ((u >> 16) & 1u);   // round-to-nearest-even
    return (u16)(u >> 16);
}

// One wave per row: convert z1,z2 to bf16, compute -sq2*log2e - BIAS and fp32 diagonal.
__global__ __launch_bounds__(256) void prep_kernel(
    const float* __restrict__ z1, const float* __restrict__ z2,
    u32* __restrict__ b1, u32* __restrict__ b2,
    float* __restrict__ negsq2b, float* __restrict__ diag)
{
    int row  = blockIdx.x * 4 + (threadIdx.x >> 6);
    int lane = threadIdx.x & 63;
    float2 a = reinterpret_cast<const float2*>(z1)[row * 64 + lane];
    float2 b = reinterpret_cast<const float2*>(z2)[row * 64 + lane];
    b1[row * 64 + lane] = (u32)f2bf(a.x) | ((u32)f2bf(a.y) << 16);
    b2[row * 64 + lane] = (u32)f2bf(b.x) | ((u32)f2bf(b.y) << 16);
    float dot = a.x * b.x + a.y * b.y;
    float sq  = b.x * b.x + b.y * b.y;
    #pragma unroll
    for (int o = 32; o > 0; o >>= 1) {
        dot += __shfl_xor(dot, o);
        sq  += __shfl_xor(sq, o);
    }
    if (lane == 0) {
        negsq2b[row] = -sq * LOG2E - BIAS;
        diag[row]    = 2.0f * dot - sq;
    }
}

// R8: R7 streaming structure + EXPLICIT 2-deep software pipeline.
// R7 post-mortem: VGPR_Count=80 proved the compiler sank the av loads into the
// MFMA chain (load -> ~150cy wait -> 2 MFMA -> load...), serializing each tile.
// Here: loads for tile t+1 issue BEFORE tile t's MFMA cluster (sched_barrier(0)
// pins the cluster boundary); tile t's exp2 epilogue runs AFTER tile t+1's MFMA
// cluster (two acc sets) so acc-latency never stalls the wave. Static names
// avA/avB, accA/accB (rule #20). The compiler's own vmcnt(8) before first use
// of a tile is the counted wait (T4) -- prefetch stays in flight.
__global__ __launch_bounds__(256) void score_kernel(
    const u16* __restrict__ b1, const u16* __restrict__ b2,
    const float* __restrict__ negsq2b, float* __restrict__ partS)
{
    __shared__ alignas(16) float nqs[CHUNK];       // 1 KB
    const int tid  = threadIdx.x;
    const int lane = tid & 63;
    const int wid  = tid >> 6;
    const int r    = lane & 31, hi = lane >> 5;

    const int f     = blockIdx.x;
    const int chunk = (f >> 3) & 31;               // 32 chunks per XCD
    const int iblk  = (f & 7) * 4 + (f >> 8);      // 4 i-blocks per XCD (bijective)
    const int j0    = chunk * CHUNK;
    const int i0w   = iblk * 256 + wid * 64;

    // z1 fragments (B operand), register-resident: 2 spans x 8 k-slices
    uint4 zf0[8], zf1[8];
    #pragma unroll
    for (int kk = 0; kk < 8; ++kk) {
        zf0[kk] = *reinterpret_cast<const uint4*>(b1 + (size_t)(i0w + r)      * DD + kk * 16 + hi * 8);
        zf1[kk] = *reinterpret_cast<const uint4*>(b1 + (size_t)(i0w + 32 + r) * DD + kk * 16 + hi * 8);
    }
    nqs[tid] = negsq2b[j0 + tid];                  // CHUNK == blockDim == 256
    __syncthreads();                               // once; nqs visible to all waves

    const u16* bbase = b2 + (size_t)(j0 + r) * DD + hi * 8;

    f32x2 sA0 = {0.f, 0.f}, sA1 = {0.f, 0.f}, sB0 = {0.f, 0.f}, sB1 = {0.f, 0.f};
    const f32x2 c2 = {2.0f * LOG2E, 2.0f * LOG2E};

    uint4 avA[8], avB[8];
    f32x16 accA0, accA1, accB0, accB1;

    auto loadTile = [&](uint4* av, int t) {
        const u16* p = bbase + (size_t)t * 32 * DD;
        #pragma unroll
        for (int kk = 0; kk < 8; ++kk)
            av[kk] = *reinterpret_cast<const uint4*>(p + kk * 16);
        __builtin_amdgcn_sched_barrier(0);         // loads may not sink past here
    };
    auto mfmaTile = [&](f32x16& a0, f32x16& a1, const uint4* av) {
        a0 = {0.f}; a1 = {0.f};
        #pragma unroll
        for (int kk = 0; kk < 8; ++kk) {
            a0 = __builtin_amdgcn_mfma_f32_32x32x16_bf16(
                     __builtin_bit_cast(bf16x8, av[kk]), __builtin_bit_cast(bf16x8, zf0[kk]), a0, 0, 0, 0);
            a1 = __builtin_amdgcn_mfma_f32_32x32x16_bf16(
                     __builtin_bit_cast(bf16x8, av[kk]), __builtin_bit_cast(bf16x8, zf1[kk]), a1, 0, 0, 0);
        }
    };
    auto epiTile = [&](const f32x16& a0, const f32x16& a1, int t) {
        const float* nqb = &nqs[t * 32 + 4 * hi];
        float4 nq0 = *reinterpret_cast<const float4*>(nqb);
        float4 nq1 = *reinterpret_cast<const float4*>(nqb + 8);
        float4 nq2 = *reinterpret_cast<const float4*>(nqb + 16);
        float4 nq3 = *reinterpret_cast<const float4*>(nqb + 24);
        const float4 nqm[4] = {nq0, nq1, nq2, nq3};
        #pragma unroll
        for (int m = 0; m < 4; ++m) {
            f32x2 n01 = {nqm[m].x, nqm[m].y}, n23 = {nqm[m].z, nqm[m].w};
            f32x2 a01 = {a0[4*m],   a0[4*m+1]}, a23 = {a0[4*m+2], a0[4*m+3]};
            f32x2 t01 = a01 * c2 + n01, t23 = a23 * c2 + n23;
            sA0.x += __builtin_amdgcn_exp2f(t01.x);
            sA0.y += __builtin_amdgcn_exp2f(t01.y);
            sA1.x += __builtin_amdgcn_exp2f(t23.x);
            sA1.y += __builtin_amdgcn_exp2f(t23.y);
            f32x2 b01 = {a1[4*m],   a1[4*m+1]}, b23 = {a1[4*m+2], a1[4*m+3]};
            f32x2 u01 = b01 * c2 + n01, u23 = b23 * c2 + n23;
            sB0.x += __builtin_amdgcn_exp2f(u01.x);
            sB0.y += __builtin_amdgcn_exp2f(u01.y);
            sB1.x += __builtin_amdgcn_exp2f(u23.x);
            sB1.y += __builtin_amdgcn_exp2f(u23.y);
        }
    };

    // software pipeline: load(t+1) || mfma(t) || epi(t-1)
    loadTile(avA, 0);
    mfmaTile(accA0, accA1, avA);
    loadTile(avB, 1);
    #pragma unroll
    for (int t = 1; t < NTJ; t += 2) {
        if (t + 1 < NTJ) loadTile(avA, t + 1);
        mfmaTile(accB0, accB1, avB);
        epiTile(accA0, accA1, t - 1);
        if (t + 2 < NTJ) loadTile(avB, t + 2);
        if (t + 1 < NTJ) mfmaTile(accA0, accA1, avA);
        epiTile(accB0, accB1, t);
    }

    float sum0 = (sA0.x + sA0.y) + (sA1.x + sA1.y);
    float sum1 = (sB0.x + sB0.y) + (sB1.x + sB1.y);
    sum0 += __shfl_xor(sum0, 32);          // combine hi=0/1 j-halves per i
    sum1 += __shfl_xor(sum1, 32);
    if (hi == 0) {
        partS[(size_t)chunk * NN + i0w + r]      = sum0;
        partS[(size_t)chunk * NN + i0w + 32 + r] = sum1;
    }
}

// Combine the 32 column-chunk partials per row, form lse - diag, block-reduce.
__global__ __launch_bounds__(256) void finalize1_kernel(
    const float* __restrict__ partS, const float* __restrict__ diag,
    float* __restrict__ blocksum)
{
    __shared__ float red[4];
    int r = blockIdx.x * 256 + threadIdx.x;
    float s = 0.f;
    #pragma unroll
    for (int c = 0; c < CCH; ++c) s += partS[(size_t)c * NN + r];
    float lse = (BIAS + __builtin_amdgcn_logf(s)) * LN2F;   // v_log_f32 = log2
    float acc = lse - diag[r];
    #pragma unroll
    for (int o = 32; o > 0; o >>= 1) acc += __shfl_xor(acc, o);
    int lane = threadIdx.x & 63, wid = threadIdx.x >> 6;
    if (lane == 0) red[wid] = acc;
    __syncthreads();
    if (threadIdx.x == 0)
        blocksum[blockIdx.x] = red[0] + red[1] + red[2] + red[3];
}

__global__ void finalize2_kernel(const float* __restrict__ blocksum, float* __restrict__ out)
{
    int lane = threadIdx.x;
    float v = (lane < 32) ? blocksum[lane] : 0.f;
    #pragma unroll
    for (int o = 32; o > 0; o >>= 1) v += __shfl_xor(v, o);
    if (lane == 0) out[0] = v * (1.0f / (float)NN);
}

extern "C" void kernel_launch(void* const* d_in, const int* in_sizes, int n_in,
                              void* d_out, int out_size, void* d_ws, size_t ws_size,
                              hipStream_t stream)
{
    const float* z1 = (const float*)d_in[0];
    const float* z2 = (const float*)d_in[1];
    char* ws = (char*)d_ws;

    const size_t bf_bytes = (size_t)NN * DD * 2;   // 2 MB each
    u32*   b1       = (u32*)ws;
    u32*   b2       = (u32*)(ws + bf_bytes);
    float* negsq2b  = (float*)(ws + 2 * bf_bytes);
    float* diag     = (float*)(ws + 2 * bf_bytes + (size_t)NN * 4);
    float* partS    = (float*)(ws + 2 * bf_bytes + (size_t)NN * 8);
    float* blocksum = (float*)(ws + 2 * bf_bytes + (size_t)NN * 8 + (size_t)CCH * NN * 4);
    float* out      = (float*)d_out;

    prep_kernel<<<NN / 4, 256, 0, stream>>>(z1, z2, b1, b2, negsq2b, diag);
    score_kernel<<<CCH * NIB, 256, 0, stream>>>((const u16*)b1, (const u16*)b2, negsq2b, partS);
    finalize1_kernel<<<NN / 256, 256, 0, stream>>>(partS, diag, blocksum);
    finalize2_kernel<<<1, 64, 0, stream>>>(blocksum, out);
}

// Round 9
// 39.153 us; speedup vs baseline: 1.4485x; 1.4485x over previous
//
#include <hip/hip_runtime.h>
#include <hip/hip_bf16.h>

typedef unsigned int   u32;
typedef unsigned short u16;

#define NN   8192
#define DD   128
#define CCH  32            // column chunks
#define CHUNK (NN / CCH)   // 256 columns per block (== blockDim)
#define JT   64            // j-tile staged in LDS
#define NT   (CHUNK / JT)  // 4 tiles per block
#define NIB  (NN / 256)    // 32 i-blocks

#define LOG2E 1.4426950408889634f
#define LN2F  0.6931471805599453f
#define BIAS  32.0f

typedef __bf16 bf16x8 __attribute__((ext_vector_type(8)));
typedef float  f32x16 __attribute__((ext_vector_type(16)));
typedef float  f32x2  __attribute__((ext_vector_type(2)));

__device__ __forceinline__ u16 f2bf(float x) {
    u32 u = __float_as_uint(x);
    u += 0x7fffu + ((u >> 16) & 1u);   // round-to-nearest-even
    return (u16)(u >> 16);
}

// One wave per row: convert z1,z2 to bf16, compute -sq2*log2e - BIAS and fp32 diagonal.
// Block 0 zeroes the finalize ticket (stream-ordered before finalize1).
__global__ __launch_bounds__(256) void prep_kernel(
    const float* __restrict__ z1, const float* __restrict__ z2,
    u32* __restrict__ b1, u32* __restrict__ b2,
    float* __restrict__ negsq2b, float* __restrict__ diag, u32* __restrict__ ctrl)
{
    if (blockIdx.x == 0 && threadIdx.x == 0) ctrl[0] = 0;
    int row  = blockIdx.x * 4 + (threadIdx.x >> 6);
    int lane = threadIdx.x & 63;
    float2 a = reinterpret_cast<const float2*>(z1)[row * 64 + lane];
    float2 b = reinterpret_cast<const float2*>(z2)[row * 64 + lane];
    b1[row * 64 + lane] = (u32)f2bf(a.x) | ((u32)f2bf(a.y) << 16);
    b2[row * 64 + lane] = (u32)f2bf(b.x) | ((u32)f2bf(b.y) << 16);
    float dot = a.x * b.x + a.y * b.y;
    float sq  = b.x * b.x + b.y * b.y;
    #pragma unroll
    for (int o = 32; o > 0; o >>= 1) {
        dot += __shfl_xor(dot, o);
        sq  += __shfl_xor(sq, o);
    }
    if (lane == 0) {
        negsq2b[row] = -sq * LOG2E - BIAS;
        diag[row]    = 2.0f * dot - sq;
    }
}

// R9 = R6 structure + counted-vmcnt pipeline (T3/T4) + setprio (T5).
// R6 was the guide's "2-phase" schedule (sync drains vmcnt(0) every tile) --
// measured ~30% of pipe floor, matching m233's 2-phase signature. Here: 3 LDS
// buffers, ONE s_barrier per tile, per-wave s_waitcnt vmcnt(4) so the next
// tile's 4 stage-loads stay in flight ACROSS the barrier (vmcnt(0) only at the
// last tile). Rendezvous logic: each wave passes the barrier only after its own
// tile-t loads retired; all waves at barrier => tile t fully in LDS.
// Everything else (XCD swizzle, swizzled global_load_lds, epilogue) = R6.
__global__ __launch_bounds__(256) void score_kernel(
    const u16* __restrict__ b1, const u16* __restrict__ b2,
    const float* __restrict__ negsq2b, float* __restrict__ partS)
{
    __shared__ alignas(16) u16 tile[3][JT * DD];   // 3 x 16 KB
    __shared__ alignas(16) float nqs[CHUNK];       // 1 KB
    const int tid  = threadIdx.x;
    const int lane = tid & 63;
    const int wid  = tid >> 6;
    const int r    = lane & 31, hi = lane >> 5;

    const int f     = blockIdx.x;
    const int chunk = (f >> 3) & 31;               // 32 chunks per XCD
    const int iblk  = (f & 7) * 4 + (f >> 8);      // 4 i-blocks per XCD (bijective)
    const int j0    = chunk * CHUNK;
    const int i0w   = iblk * 256 + wid * 64;

    // z1 fragments (B operand), register-resident: 2 spans x 8 k-slices
    bf16x8 zf0[8], zf1[8];
    #pragma unroll
    for (int kk = 0; kk < 8; ++kk) {
        zf0[kk] = *reinterpret_cast<const bf16x8*>(b1 + (size_t)(i0w + r)      * DD + kk * 16 + hi * 8);
        zf1[kk] = *reinterpret_cast<const bf16x8*>(b1 + (size_t)(i0w + 32 + r) * DD + kk * 16 + hi * 8);
    }
    nqs[tid] = negsq2b[j0 + tid];                  // CHUNK == blockDim == 256
    __syncthreads();                               // one-time full drain; nqs+zf ready

    const int sl   = lane & 15;    // staging slot
    const int rrow = lane >> 4;    // staging row-within-4

    auto stage = [&](int t, u16* dst_base) {
        #pragma unroll
        for (int u = 0; u < 4; ++u) {
            int row   = wid * 16 + u * 4 + rrow;           // local row 0..63
            int gslot = sl ^ (row & 15);                   // inverse-swizzled source (rule 21)
            const u16* src = b2 + (size_t)(j0 + t * JT + row) * DD + gslot * 8;
            __builtin_amdgcn_global_load_lds(
                (const __attribute__((address_space(1))) void*)src,
                (__attribute__((address_space(3))) void*)(dst_base + (wid * 16 + u * 4) * DD),
                16, 0, 0);
        }
    };

    stage(0, tile[0]);
    stage(1, tile[1]);

    float s0 = 0.f, s1 = 0.f, s2 = 0.f, s3 = 0.f;
    const f32x2 C2v = {2.0f * LOG2E, 2.0f * LOG2E};
    const int sw = r & 15;   // read-side swizzle key

    #pragma unroll
    for (int t = 0; t < NT; ++t) {
        // counted wait: own tile-t loads retired; tile-(t+1)'s 4 stay in flight
        if (t < NT - 1) asm volatile("s_waitcnt vmcnt(4)" ::: "memory");
        else            asm volatile("s_waitcnt vmcnt(0)" ::: "memory");
        __builtin_amdgcn_s_barrier();
        __builtin_amdgcn_sched_barrier(0);
        if (t + 2 < NT) stage(t + 2, tile[(t + 2) % 3]);
        const u16* tp = tile[t % 3];
        #pragma unroll
        for (int jj = 0; jj < 2; ++jj) {
            const float* nqb = &nqs[t * JT + jj * 32 + 4 * hi];
            float4 nq0 = *reinterpret_cast<const float4*>(nqb);
            float4 nq1 = *reinterpret_cast<const float4*>(nqb + 8);
            float4 nq2 = *reinterpret_cast<const float4*>(nqb + 16);
            float4 nq3 = *reinterpret_cast<const float4*>(nqb + 24);
            bf16x8 av[8];
            #pragma unroll
            for (int kk = 0; kk < 8; ++kk) {
                int off = (jj * 32 + r) * DD + (((2 * kk + hi) ^ sw) << 3);
                av[kk] = *reinterpret_cast<const bf16x8*>(tp + off);
            }
            f32x16 acc0 = {0.f}; f32x16 acc1 = {0.f};
            __builtin_amdgcn_s_setprio(1);
            #pragma unroll
            for (int kk = 0; kk < 8; ++kk) {
                acc0 = __builtin_amdgcn_mfma_f32_32x32x16_bf16(av[kk], zf0[kk], acc0, 0, 0, 0);
                acc1 = __builtin_amdgcn_mfma_f32_32x32x16_bf16(av[kk], zf1[kk], acc1, 0, 0, 0);
            }
            __builtin_amdgcn_s_setprio(0);
            const float nqa[16] = {nq0.x, nq0.y, nq0.z, nq0.w,
                                   nq1.x, nq1.y, nq1.z, nq1.w,
                                   nq2.x, nq2.y, nq2.z, nq2.w,
                                   nq3.x, nq3.y, nq3.z, nq3.w};
            #pragma unroll
            for (int q = 0; q < 8; ++q) {
                f32x2 n2 = {nqa[2 * q], nqa[2 * q + 1]};
                f32x2 a0 = {acc0[2 * q], acc0[2 * q + 1]};
                f32x2 t0 = a0 * C2v + n2;
                s0 += __builtin_amdgcn_exp2f(t0.x);
                s1 += __builtin_amdgcn_exp2f(t0.y);
                f32x2 a1 = {acc1[2 * q], acc1[2 * q + 1]};
                f32x2 t1 = a1 * C2v + n2;
                s2 += __builtin_amdgcn_exp2f(t1.x);
                s3 += __builtin_amdgcn_exp2f(t1.y);
            }
        }
    }

    float sum0 = s0 + s1, sum1 = s2 + s3;
    sum0 += __shfl_xor(sum0, 32);          // combine hi=0/1 j-halves per i
    sum1 += __shfl_xor(sum1, 32);
    if (hi == 0) {
        partS[(size_t)chunk * NN + i0w + r]      = sum0;
        partS[(size_t)chunk * NN + i0w + 32 + r] = sum1;
    }
}

// Combine the 32 column-chunk partials per row, lse - diag, block-reduce;
// the LAST block (atomic ticket) sums the 32 block results in fixed order.
// No spin: the last arrival only READS data already release-fenced.
__global__ __launch_bounds__(256) void finalize1_kernel(
    const float* __restrict__ partS, const float* __restrict__ diag,
    float* __restrict__ blocksum, u32* __restrict__ ctrl, float* __restrict__ out)
{
    __shared__ float red[4];
    __shared__ u32 ticket;
    int r = blockIdx.x * 256 + threadIdx.x;
    float s = 0.f;
    #pragma unroll
    for (int c = 0; c < CCH; ++c) s += partS[(size_t)c * NN + r];
    float lse = (BIAS + __builtin_amdgcn_logf(s)) * LN2F;   // v_log_f32 = log2
    float acc = lse - diag[r];
    #pragma unroll
    for (int o = 32; o > 0; o >>= 1) acc += __shfl_xor(acc, o);
    int lane = threadIdx.x & 63, wid = threadIdx.x >> 6;
    if (lane == 0) red[wid] = acc;
    __syncthreads();
    if (threadIdx.x == 0) {
        blocksum[blockIdx.x] = red[0] + red[1] + red[2] + red[3];
        __threadfence();                           // release blocksum
        ticket = atomicAdd(ctrl, 1u);
    }
    __syncthreads();
    if (ticket == NIB - 1 && threadIdx.x == 0) {   // last arrival: all 31 others fenced
        __threadfence();                           // acquire
        float v = 0.f;
        #pragma unroll
        for (int c = 0; c < NIB; ++c) v += blocksum[c];
        out[0] = v * (1.0f / (float)NN);
    }
}

extern "C" void kernel_launch(void* const* d_in, const int* in_sizes, int n_in,
                              void* d_out, int out_size, void* d_ws, size_t ws_size,
                              hipStream_t stream)
{
    const float* z1 = (const float*)d_in[0];
    const float* z2 = (const float*)d_in[1];
    char* ws = (char*)d_ws;

    const size_t bf_bytes = (size_t)NN * DD * 2;   // 2 MB each
    u32*   b1       = (u32*)ws;
    u32*   b2       = (u32*)(ws + bf_bytes);
    float* negsq2b  = (float*)(ws + 2 * bf_bytes);
    float* diag     = (float*)(ws + 2 * bf_bytes + (size_t)NN * 4);
    float* partS    = (float*)(ws + 2 * bf_bytes + (size_t)NN * 8);
    float* blocksum = (float*)(ws + 2 * bf_bytes + (size_t)NN * 8 + (size_t)CCH * NN * 4);
    u32*   ctrl     = (u32*)(ws + 2 * bf_bytes + (size_t)NN * 8 + (size_t)CCH * NN * 4 + 256);
    float* out      = (float*)d_out;

    prep_kernel<<<NN / 4, 256, 0, stream>>>(z1, z2, b1, b2, negsq2b, diag, ctrl);
    score_kernel<<<CCH * NIB, 256, 0, stream>>>((const u16*)b1, (const u16*)b2, negsq2b, partS);
    finalize1_kernel<<<NIB, 256, 0, stream>>>(partS, diag, blocksum, ctrl, out);
}